// Round 4
// baseline (227.638 us; speedup 1.0000x reference)
//
#include <hip/hip_runtime.h>
#include <hip/hip_bf16.h>
#include <stdint.h>

#define TKS    4096   // tokens = 2*2048
#define KD     4096   // in_features
#define NSF    410    // split_f
#define NPARTS 10
#define OUTF   4096

typedef unsigned short u16;
typedef __attribute__((ext_vector_type(8))) short bf16x8;
typedef __attribute__((ext_vector_type(4))) float f32x4;

// ---- workspace layout (sx/gc carved from unused bsw slabs 448..511) ----
#define WS_XB  0                                     // u16[4096*4096]  granule bf16 x (32-row tiles)
#define WS_BSW ((size_t)TKS * KD * 2)                // u16[512*4096]   granule bf16 Wfc (64-row tiles)
#define WS_SX  (WS_BSW + (size_t)448 * 512 * 8 * 2)  // f32[4096*10]    sx
#define WS_GC  (WS_SX + (size_t)TKS * NPARTS * 4)    // f32[448*12]     G (cols 0..9) + c (col 10)

__device__ inline u16 f2bf(float f) {
    union { __hip_bfloat16 b; u16 u; } cv;
    cv.b = __float2bfloat16(f);
    return cv.u;
}

// 64-row tile granule g in [0,512): slot=g>>6 = hi*4+ks*2+lo
// row = hi*32+lo*16+(g&15) ; col = ks*32+((g>>4)&3)*8   (conflict-free, proven)
__device__ inline int g_row(int g) { int s = g >> 6; return (s >> 2) * 32 + (s & 1) * 16 + (g & 15); }
__device__ inline int g_col(int g) { int s = g >> 6; return ((s >> 1) & 1) * 32 + ((g >> 4) & 3) * 8; }

// ============ prep: ALL preprocessing in ONE launch ==========================
// grid 8782 blocks x 256 thr, partitioned:
//   [0,8192)      retile_x : x (f32) -> xb (bf16 32-row granule tiles)
//   [8192,8640)   retile_b : Wfc (f32) -> bsw (bf16 64-row granule tiles)
//   [8640,8768)   sx-f32   : sx = x*Wsel^T + bsel   (raw f32 VALU, 32 tok/blk)
//   [8768,8782)   G-f32    : G = Wfc*Wexp, c = Wfc*bexp + bfc (32 f/blk)
__global__ __launch_bounds__(256) void prep(const float* __restrict__ x,
                                            const float* __restrict__ Wsel,
                                            const float* __restrict__ bsel,
                                            const float* __restrict__ Wexp,
                                            const float* __restrict__ bexp,
                                            const float* __restrict__ Wfc,
                                            const float* __restrict__ bfc,
                                            u16* __restrict__ xb,
                                            u16* __restrict__ bsw,
                                            float* __restrict__ sxb,
                                            float* __restrict__ gc) {
    const int bid = blockIdx.x;
    const int tid = threadIdx.x;

    if (bid < 8192) {
        // -------- retile_x (unchanged logic) --------
        const int kt = bid & 63, tb = bid >> 6;     // tb 0..127
        const int g = tid;                          // granule 0..255
        const int slot = g >> 6;                    // ks*2+lo
        const int row = (slot & 1) * 16 + (g & 15);
        const int col = (slot >> 1) * 32 + ((g >> 4) & 3) * 8;
        const float* src = x + (size_t)(tb * 32 + row) * KD + kt * 64 + col;
        float4 v0 = *(const float4*)src;
        float4 v1 = *(const float4*)(src + 4);
        u16 h[8] = { f2bf(v0.x), f2bf(v0.y), f2bf(v0.z), f2bf(v0.w),
                     f2bf(v1.x), f2bf(v1.y), f2bf(v1.z), f2bf(v1.w) };
        *(uint4*)&xb[((size_t)(tb * 64 + kt) * 256 + g) * 8] = *(uint4*)h;

    } else if (bid < 8640) {
        // -------- retile_b (unchanged logic) --------
        const int b2 = bid - 8192;
        const int kt = b2 & 63, rb = b2 >> 6;       // rb 0..6
        u16* tout = bsw + ((size_t)(rb * 64 + kt) * 512) * 8;
#pragma unroll
        for (int j = 0; j < 2; ++j) {
            const int g = j * 256 + tid;
            const int r = rb * 64 + g_row(g);
            uint4 pk = make_uint4(0u, 0u, 0u, 0u);
            if (r < NSF) {
                const float* src = Wfc + (size_t)r * KD + kt * 64 + g_col(g);
                float4 v0 = *(const float4*)src;
                float4 v1 = *(const float4*)(src + 4);
                u16 h[8] = { f2bf(v0.x), f2bf(v0.y), f2bf(v0.z), f2bf(v0.w),
                             f2bf(v1.x), f2bf(v1.y), f2bf(v1.z), f2bf(v1.w) };
                pk = *(uint4*)h;
            }
            *(uint4*)&tout[(size_t)g * 8] = pk;
        }

    } else if (bid < 8768) {
        // -------- sx-f32: wave w owns 8 tokens, lanes split K 64-way --------
        const int b3 = bid - 8640;                  // 0..127
        const int w = tid >> 6, lane = tid & 63;
        const int t0 = b3 * 32 + w * 8;
        float acc[8][NPARTS];
#pragma unroll
        for (int t = 0; t < 8; ++t)
#pragma unroll
            for (int n = 0; n < NPARTS; ++n) acc[t][n] = 0.f;

        for (int k4 = 0; k4 < 16; ++k4) {           // k = k4*256 + lane*4
            const int k = k4 * 256 + lane * 4;
            float4 ws[NPARTS];
#pragma unroll
            for (int n = 0; n < NPARTS; ++n)
                ws[n] = *(const float4*)&Wsel[(size_t)n * KD + k];
#pragma unroll
            for (int t = 0; t < 8; ++t) {
                float4 xv = *(const float4*)&x[(size_t)(t0 + t) * KD + k];
#pragma unroll
                for (int n = 0; n < NPARTS; ++n)
                    acc[t][n] += xv.x * ws[n].x + xv.y * ws[n].y
                               + xv.z * ws[n].z + xv.w * ws[n].w;
            }
        }
        // butterfly reduce across 64 K-lanes
#pragma unroll
        for (int s = 1; s < 64; s <<= 1)
#pragma unroll
            for (int t = 0; t < 8; ++t)
#pragma unroll
                for (int n = 0; n < NPARTS; ++n)
                    acc[t][n] += __shfl_xor(acc[t][n], s);
        if (lane == 0) {
#pragma unroll
            for (int t = 0; t < 8; ++t)
#pragma unroll
                for (int n = 0; n < NPARTS; ++n)
                    sxb[(size_t)(t0 + t) * NPARTS + n] = acc[t][n] + bsel[n];
        }

    } else {
        // -------- G-f32: wave w owns 8 f-rows; col 10 = c (bexp dot) --------
        const int b4 = bid - 8768;                  // 0..13
        const int w = tid >> 6, lane = tid & 63;
        const int f0 = b4 * 32 + w * 8;
        float acc[8][11];
#pragma unroll
        for (int t = 0; t < 8; ++t)
#pragma unroll
            for (int n = 0; n < 11; ++n) acc[t][n] = 0.f;

        for (int k4 = 0; k4 < 16; ++k4) {
            const int k = k4 * 256 + lane * 4;
            float we[4][11];
#pragma unroll
            for (int j = 0; j < 4; ++j) {
#pragma unroll
                for (int n = 0; n < NPARTS; ++n)
                    we[j][n] = Wexp[(size_t)(k + j) * NPARTS + n];
                we[j][10] = bexp[k + j];
            }
#pragma unroll
            for (int t = 0; t < 8; ++t) {
                const int f = f0 + t;
                float4 xv = (f < NSF) ? *(const float4*)&Wfc[(size_t)f * KD + k]
                                      : make_float4(0.f, 0.f, 0.f, 0.f);
#pragma unroll
                for (int n = 0; n < 11; ++n)
                    acc[t][n] += xv.x * we[0][n] + xv.y * we[1][n]
                               + xv.z * we[2][n] + xv.w * we[3][n];
            }
        }
#pragma unroll
        for (int s = 1; s < 64; s <<= 1)
#pragma unroll
            for (int t = 0; t < 8; ++t)
#pragma unroll
                for (int n = 0; n < 11; ++n)
                    acc[t][n] += __shfl_xor(acc[t][n], s);
        if (lane == 0) {
#pragma unroll
            for (int t = 0; t < 8; ++t) {
                const int f = f0 + t;
#pragma unroll
                for (int n = 0; n < NPARTS; ++n)
                    gc[(size_t)f * 12 + n] = (f < NSF) ? acc[t][n] : 0.f;
                gc[(size_t)f * 12 + 10] = (f < NSF) ? acc[t][10] + bfc[f] : 0.f;
            }
        }
    }
}

// ============ main: zero-LDS K-loop, depth-4 register pipeline ===============
// Tile per wave: 64 tok x 32 f, 4-way K-split (wave kh covers kt in [kh*16,kh*16+16)).
// Per 32-K half-step: 4 av x 2 bv -> 8 MFMA from 6 loads; 4 buffers = 3 half-steps
// of loads in flight (~18 loads) to cover the ~300-500cy L2/L3 latency that
// R3's 2-deep pipeline exposed (MfmaUtil 7.4%, all pipes idle).
// grid 832 = 13 f2 x 64 tb (stride 64 % 8 == 0 keeps same-tb on one XCD).
#define A_IDX(kt, mi, ks) ((((size_t)(tb * 2 + ((mi) >> 1)) * 64 + (size_t)(kt)) * 256 \
                            + ((ks) * 2 + ((mi) & 1)) * 64 + lane) * 8)
#define B_IDX(kt, nj, ks) (((size_t)(fb * 64 + (kt)) * 512 \
                            + (wf * 4 + (ks) * 2 + (nj)) * 64 + lane) * 8)

__global__ __launch_bounds__(256) void main_kernel(const u16* __restrict__ xb,
                                                   const u16* __restrict__ bsw,
                                                   const float* __restrict__ sxb,
                                                   const float* __restrict__ gc,
                                                   float* __restrict__ out) {
    // [mi][donor kh][row16][f pad 34]: stride 34 -> bank = (ml+8q)%32, 2-way = free
    __shared__ float red[4][4][16][34];   // 34.8 KB
    __shared__ float sxt[64][NPARTS];     // 2.5 KB
    __shared__ float gt[32][12];          // 1.5 KB

    const int tid = threadIdx.x;
    const int f2 = blockIdx.x >> 6;     // 0..12  (f2=13 would be all fg>=410)
    const int tb = blockIdx.x & 63;     // 0..63  (64-token tiles)
    const int lane = tid & 63;
    const int kh = tid >> 6;            // K-split wave id 0..3
    const int q = lane >> 4, ml = lane & 15;
    const int fb = f2 >> 1, wf = f2 & 1;

    f32x4 acc[4][2];
#pragma unroll
    for (int mi = 0; mi < 4; ++mi)
#pragma unroll
        for (int nj = 0; nj < 2; ++nj) acc[mi][nj] = (f32x4){0.f,0.f,0.f,0.f};

    bf16x8 fa[4][4], fbv[4][2];

#define LOADAB(p, kt, ks) do {                                            \
        _Pragma("unroll")                                                 \
        for (int mi = 0; mi < 4; ++mi)                                    \
            fa[p][mi] = *(const bf16x8*)&xb[A_IDX((kt), mi, (ks))];       \
        _Pragma("unroll")                                                 \
        for (int nj = 0; nj < 2; ++nj)                                    \
            fbv[p][nj] = *(const bf16x8*)&bsw[B_IDX((kt), nj, (ks))];     \
    } while (0)

#define MFMAS(p) do {                                                     \
        _Pragma("unroll")                                                 \
        for (int mi = 0; mi < 4; ++mi)                                    \
            _Pragma("unroll")                                             \
            for (int nj = 0; nj < 2; ++nj)                                \
                acc[mi][nj] = __builtin_amdgcn_mfma_f32_16x16x32_bf16(    \
                    fa[p][mi], fbv[p][nj], acc[mi][nj], 0, 0, 0);         \
    } while (0)

    // half-step s in [0,32): kt = kh*16 + (s>>1), ks = s&1
#define LD(p, s) LOADAB((p), kh * 16 + ((s) >> 1), (s) & 1)

    LD(0, 0); LD(1, 1); LD(2, 2);
#pragma unroll
    for (int s = 0; s < 32; ++s) {
        if (s + 3 < 32) LD((s + 3) & 3, s + 3);
        MFMAS(s & 3);
    }
#undef LD
#undef LOADAB
#undef MFMAS

    // ---- K-reduce: wave kh publishes partials; owns row group kh after barrier
#pragma unroll
    for (int mi = 0; mi < 4; ++mi)
#pragma unroll
        for (int nj = 0; nj < 2; ++nj)
#pragma unroll
            for (int r = 0; r < 4; ++r)
                red[mi][kh][q * 4 + r][nj * 16 + ml] = acc[mi][nj][r];

    // stage sx / G tables (global -> LDS) while reduce data lands
    for (int i = tid; i < 64 * NPARTS; i += 256)
        sxt[i / NPARTS][i % NPARTS] = sxb[((size_t)tb * 64 + i / NPARTS) * NPARTS + i % NPARTS];
    for (int i = tid; i < 32 * 11; i += 256)
        gt[i / 11][i % 11] = gc[((size_t)f2 * 32 + i / 11) * 12 + i % 11];
    __syncthreads();

    // ---- epilogue: wave kh stores rows kh*16 .. kh*16+15 ----
#pragma unroll
    for (int nj = 0; nj < 2; ++nj) {
        const int fl = nj * 16 + ml;
        const int fg = f2 * 32 + fl;
        if (fg >= NSF) continue;
        const float cv = gt[fl][10];
        float gv[NPARTS];
#pragma unroll
        for (int n = 0; n < NPARTS; ++n) gv[n] = gt[fl][n];
#pragma unroll
        for (int r = 0; r < 4; ++r) {
            const int tl = kh * 16 + q * 4 + r;
            const float v = red[kh][0][q * 4 + r][fl] + red[kh][1][q * 4 + r][fl]
                          + red[kh][2][q * 4 + r][fl] + red[kh][3][q * 4 + r][fl];
            const float av = v + cv;
            float* orow = out + (size_t)(tb * 64 + tl) * OUTF;
#pragma unroll
            for (int n = 0; n < NPARTS; ++n) {
                const int j = n * NSF + fg;
                if (j < OUTF) orow[j] = av + sxt[tl][n] * gv[n];
            }
        }
    }
}

extern "C" void kernel_launch(void* const* d_in, const int* in_sizes, int n_in,
                              void* d_out, int out_size, void* d_ws, size_t ws_size,
                              hipStream_t stream) {
    const float* x    = (const float*)d_in[0];
    const float* Wsel = (const float*)d_in[1];
    const float* bsel = (const float*)d_in[2];
    const float* Wexp = (const float*)d_in[3];
    const float* bexp = (const float*)d_in[4];
    const float* Wfc  = (const float*)d_in[5];
    const float* bfc  = (const float*)d_in[6];
    float* out = (float*)d_out;

    char* ws = (char*)d_ws;
    u16* xb    = (u16*)(ws + WS_XB);
    u16* bsw   = (u16*)(ws + WS_BSW);
    float* sxb = (float*)(ws + WS_SX);
    float* gcv = (float*)(ws + WS_GC);

    // launch 1: all preprocessing (retile_x | retile_b | sx | G/c)
    prep<<<dim3(8192 + 448 + 128 + 14), dim3(256), 0, stream>>>(
        x, Wsel, bsel, Wexp, bexp, Wfc, bfc, xb, bsw, sxb, gcv);
    // launch 2: main GEMM + fused epilogue
    main_kernel<<<dim3(13 * 64), dim3(256), 0, stream>>>(xb, bsw, sxb, gcv, out);
}

// Round 5
// 216.741 us; speedup vs baseline: 1.0503x; 1.0503x over previous
//
#include <hip/hip_runtime.h>
#include <hip/hip_bf16.h>
#include <stdint.h>

#define TKS    4096   // tokens = 2*2048
#define KD     4096   // in_features
#define NSF    410    // split_f
#define NPARTS 10
#define OUTF   4096

typedef unsigned short u16;
typedef __attribute__((ext_vector_type(8))) short bf16x8;
typedef __attribute__((ext_vector_type(4))) float f32x4;

// ---- workspace layout (sx/gc carved from unused bsw slabs 448..511) ----
#define WS_XB  0                                     // u16[4096*4096]  granule bf16 x (32-row tiles)
#define WS_BSW ((size_t)TKS * KD * 2)                // u16[512*4096]   granule bf16 Wfc (64-row tiles)
#define WS_SX  (WS_BSW + (size_t)448 * 512 * 8 * 2)  // f32[4096*10]    sx
#define WS_GC  (WS_SX + (size_t)TKS * NPARTS * 4)    // f32[448*12]     G (cols 0..9) + c (col 10)

__device__ inline u16 f2bf(float f) {
    union { __hip_bfloat16 b; u16 u; } cv;
    cv.b = __float2bfloat16(f);
    return cv.u;
}

// 64-row tile granule g in [0,512): slot=g>>6 = hi*4+ks*2+lo
// row = hi*32+lo*16+(g&15) ; col = ks*32+((g>>4)&3)*8   (conflict-free, proven)
__device__ inline int g_row(int g) { int s = g >> 6; return (s >> 2) * 32 + (s & 1) * 16 + (g & 15); }
__device__ inline int g_col(int g) { int s = g >> 6; return ((s >> 1) & 1) * 32 + ((g >> 4) & 3) * 8; }

// ============ prep: ALL preprocessing in ONE launch ==========================
// grid 8782 blocks x 256 thr. Long-latency few-block jobs FIRST so they start
// at t=0 and hide under the retile bulk (R4 had them last -> serial tail):
//   [0,128)          sx-f32   : sx = x*Wsel^T + bsel   (32 tok/blk)
//   [128,142)        G-f32    : G = Wfc*Wexp, c = Wfc*bexp + bfc (32 f/blk)
//   [142,8334)       retile_x : x (f32) -> xb (bf16 32-row granule tiles)
//   [8334,8782)      retile_b : Wfc (f32) -> bsw (bf16 64-row granule tiles)
__global__ __launch_bounds__(256) void prep(const float* __restrict__ x,
                                            const float* __restrict__ Wsel,
                                            const float* __restrict__ bsel,
                                            const float* __restrict__ Wexp,
                                            const float* __restrict__ bexp,
                                            const float* __restrict__ Wfc,
                                            const float* __restrict__ bfc,
                                            u16* __restrict__ xb,
                                            u16* __restrict__ bsw,
                                            float* __restrict__ sxb,
                                            float* __restrict__ gc) {
    const int bid = blockIdx.x;
    const int tid = threadIdx.x;

    if (bid < 128) {
        // -------- sx-f32: wave w owns 8 tokens, lanes split K 64-way --------
        const int b3 = bid;                         // 0..127
        const int w = tid >> 6, lane = tid & 63;
        const int t0 = b3 * 32 + w * 8;
        float acc[8][NPARTS];
#pragma unroll
        for (int t = 0; t < 8; ++t)
#pragma unroll
            for (int n = 0; n < NPARTS; ++n) acc[t][n] = 0.f;

        for (int k4 = 0; k4 < 16; ++k4) {           // k = k4*256 + lane*4
            const int k = k4 * 256 + lane * 4;
            float4 ws[NPARTS];
#pragma unroll
            for (int n = 0; n < NPARTS; ++n)
                ws[n] = *(const float4*)&Wsel[(size_t)n * KD + k];
#pragma unroll
            for (int t = 0; t < 8; ++t) {
                float4 xv = *(const float4*)&x[(size_t)(t0 + t) * KD + k];
#pragma unroll
                for (int n = 0; n < NPARTS; ++n)
                    acc[t][n] += xv.x * ws[n].x + xv.y * ws[n].y
                               + xv.z * ws[n].z + xv.w * ws[n].w;
            }
        }
        // butterfly reduce across 64 K-lanes
#pragma unroll
        for (int s = 1; s < 64; s <<= 1)
#pragma unroll
            for (int t = 0; t < 8; ++t)
#pragma unroll
                for (int n = 0; n < NPARTS; ++n)
                    acc[t][n] += __shfl_xor(acc[t][n], s);
        if (lane == 0) {
#pragma unroll
            for (int t = 0; t < 8; ++t)
#pragma unroll
                for (int n = 0; n < NPARTS; ++n)
                    sxb[(size_t)(t0 + t) * NPARTS + n] = acc[t][n] + bsel[n];
        }

    } else if (bid < 142) {
        // -------- G-f32: wave w owns 8 f-rows; col 10 = c (bexp dot) --------
        const int b4 = bid - 128;                   // 0..13
        const int w = tid >> 6, lane = tid & 63;
        const int f0 = b4 * 32 + w * 8;
        float acc[8][11];
#pragma unroll
        for (int t = 0; t < 8; ++t)
#pragma unroll
            for (int n = 0; n < 11; ++n) acc[t][n] = 0.f;

        for (int k4 = 0; k4 < 16; ++k4) {
            const int k = k4 * 256 + lane * 4;
            float we[4][11];
#pragma unroll
            for (int j = 0; j < 4; ++j) {
#pragma unroll
                for (int n = 0; n < NPARTS; ++n)
                    we[j][n] = Wexp[(size_t)(k + j) * NPARTS + n];
                we[j][10] = bexp[k + j];
            }
#pragma unroll
            for (int t = 0; t < 8; ++t) {
                const int f = f0 + t;
                float4 xv = (f < NSF) ? *(const float4*)&Wfc[(size_t)f * KD + k]
                                      : make_float4(0.f, 0.f, 0.f, 0.f);
#pragma unroll
                for (int n = 0; n < 11; ++n)
                    acc[t][n] += xv.x * we[0][n] + xv.y * we[1][n]
                               + xv.z * we[2][n] + xv.w * we[3][n];
            }
        }
#pragma unroll
        for (int s = 1; s < 64; s <<= 1)
#pragma unroll
            for (int t = 0; t < 8; ++t)
#pragma unroll
                for (int n = 0; n < 11; ++n)
                    acc[t][n] += __shfl_xor(acc[t][n], s);
        if (lane == 0) {
#pragma unroll
            for (int t = 0; t < 8; ++t) {
                const int f = f0 + t;
#pragma unroll
                for (int n = 0; n < NPARTS; ++n)
                    gc[(size_t)f * 12 + n] = (f < NSF) ? acc[t][n] : 0.f;
                gc[(size_t)f * 12 + 10] = (f < NSF) ? acc[t][10] + bfc[f] : 0.f;
            }
        }

    } else if (bid < 8334) {
        // -------- retile_x (unchanged logic) --------
        const int b1 = bid - 142;
        const int kt = b1 & 63, tb = b1 >> 6;       // tb 0..127
        const int g = tid;                          // granule 0..255
        const int slot = g >> 6;                    // ks*2+lo
        const int row = (slot & 1) * 16 + (g & 15);
        const int col = (slot >> 1) * 32 + ((g >> 4) & 3) * 8;
        const float* src = x + (size_t)(tb * 32 + row) * KD + kt * 64 + col;
        float4 v0 = *(const float4*)src;
        float4 v1 = *(const float4*)(src + 4);
        u16 h[8] = { f2bf(v0.x), f2bf(v0.y), f2bf(v0.z), f2bf(v0.w),
                     f2bf(v1.x), f2bf(v1.y), f2bf(v1.z), f2bf(v1.w) };
        *(uint4*)&xb[((size_t)(tb * 64 + kt) * 256 + g) * 8] = *(uint4*)h;

    } else {
        // -------- retile_b (unchanged logic) --------
        const int b2 = bid - 8334;
        const int kt = b2 & 63, rb = b2 >> 6;       // rb 0..6
        u16* tout = bsw + ((size_t)(rb * 64 + kt) * 512) * 8;
#pragma unroll
        for (int j = 0; j < 2; ++j) {
            const int g = j * 256 + tid;
            const int r = rb * 64 + g_row(g);
            uint4 pk = make_uint4(0u, 0u, 0u, 0u);
            if (r < NSF) {
                const float* src = Wfc + (size_t)r * KD + kt * 64 + g_col(g);
                float4 v0 = *(const float4*)src;
                float4 v1 = *(const float4*)(src + 4);
                u16 h[8] = { f2bf(v0.x), f2bf(v0.y), f2bf(v0.z), f2bf(v0.w),
                             f2bf(v1.x), f2bf(v1.y), f2bf(v1.z), f2bf(v1.w) };
                pk = *(uint4*)h;
            }
            *(uint4*)&tout[(size_t)g * 8] = pk;
        }
    }
}

// ============ main: zero-LDS K-loop, depth-4 register pipeline ===============
// R5 change: __launch_bounds__(256, 2) grants the register budget (~150 VGPR)
// the depth-4 pipeline needs. R3/R4 ran at VGPR=52: the compiler collapsed the
// rotation to ~2 loads in flight -> ~96 exposed L2/L3 waits/wave -> 70 us.
// With 18 loads in flight at 2 waves/SIMD, exposed latency/half-step drops to
// max(0, lat - 3 half-steps of MFMA work).
// grid 832 = 13 f2 x 64 tb (stride 64 % 8 == 0 keeps same-tb on one XCD).
#define A_IDX(kt, mi, ks) ((((size_t)(tb * 2 + ((mi) >> 1)) * 64 + (size_t)(kt)) * 256 \
                            + ((ks) * 2 + ((mi) & 1)) * 64 + lane) * 8)
#define B_IDX(kt, nj, ks) (((size_t)(fb * 64 + (kt)) * 512 \
                            + (wf * 4 + (ks) * 2 + (nj)) * 64 + lane) * 8)

__global__ __launch_bounds__(256, 2) void main_kernel(const u16* __restrict__ xb,
                                                      const u16* __restrict__ bsw,
                                                      const float* __restrict__ sxb,
                                                      const float* __restrict__ gc,
                                                      float* __restrict__ out) {
    // [mi][donor kh][row16][f pad 34]: stride 34 -> bank = (ml+8q)%32, 2-way = free
    __shared__ float red[4][4][16][34];   // 34.8 KB
    __shared__ float sxt[64][NPARTS];     // 2.5 KB
    __shared__ float gt[32][12];          // 1.5 KB

    const int tid = threadIdx.x;
    const int f2 = blockIdx.x >> 6;     // 0..12  (f2=13 would be all fg>=410)
    const int tb = blockIdx.x & 63;     // 0..63  (64-token tiles)
    const int lane = tid & 63;
    const int kh = tid >> 6;            // K-split wave id 0..3
    const int q = lane >> 4, ml = lane & 15;
    const int fb = f2 >> 1, wf = f2 & 1;

    f32x4 acc[4][2];
#pragma unroll
    for (int mi = 0; mi < 4; ++mi)
#pragma unroll
        for (int nj = 0; nj < 2; ++nj) acc[mi][nj] = (f32x4){0.f,0.f,0.f,0.f};

    bf16x8 fa[4][4], fbv[4][2];

#define LOADAB(p, kt, ks) do {                                            \
        _Pragma("unroll")                                                 \
        for (int mi = 0; mi < 4; ++mi)                                    \
            fa[p][mi] = *(const bf16x8*)&xb[A_IDX((kt), mi, (ks))];       \
        _Pragma("unroll")                                                 \
        for (int nj = 0; nj < 2; ++nj)                                    \
            fbv[p][nj] = *(const bf16x8*)&bsw[B_IDX((kt), nj, (ks))];     \
    } while (0)

#define MFMAS(p) do {                                                     \
        _Pragma("unroll")                                                 \
        for (int mi = 0; mi < 4; ++mi)                                    \
            _Pragma("unroll")                                             \
            for (int nj = 0; nj < 2; ++nj)                                \
                acc[mi][nj] = __builtin_amdgcn_mfma_f32_16x16x32_bf16(    \
                    fa[p][mi], fbv[p][nj], acc[mi][nj], 0, 0, 0);         \
    } while (0)

    // half-step s in [0,32): kt = kh*16 + (s>>1), ks = s&1
#define LD(p, s) LOADAB((p), kh * 16 + ((s) >> 1), (s) & 1)

    LD(0, 0); LD(1, 1); LD(2, 2);
#pragma unroll
    for (int s = 0; s < 32; ++s) {
        if (s + 3 < 32) LD((s + 3) & 3, s + 3);
        MFMAS(s & 3);
    }
#undef LD
#undef LOADAB
#undef MFMAS

    // ---- K-reduce: wave kh publishes partials; owns row group kh after barrier
#pragma unroll
    for (int mi = 0; mi < 4; ++mi)
#pragma unroll
        for (int nj = 0; nj < 2; ++nj)
#pragma unroll
            for (int r = 0; r < 4; ++r)
                red[mi][kh][q * 4 + r][nj * 16 + ml] = acc[mi][nj][r];

    // stage sx / G tables (global -> LDS) while reduce data lands
    for (int i = tid; i < 64 * NPARTS; i += 256)
        sxt[i / NPARTS][i % NPARTS] = sxb[((size_t)tb * 64 + i / NPARTS) * NPARTS + i % NPARTS];
    for (int i = tid; i < 32 * 11; i += 256)
        gt[i / 11][i % 11] = gc[((size_t)f2 * 32 + i / 11) * 12 + i % 11];
    __syncthreads();

    // ---- epilogue: wave kh stores rows kh*16 .. kh*16+15 ----
#pragma unroll
    for (int nj = 0; nj < 2; ++nj) {
        const int fl = nj * 16 + ml;
        const int fg = f2 * 32 + fl;
        if (fg >= NSF) continue;
        const float cv = gt[fl][10];
        float gv[NPARTS];
#pragma unroll
        for (int n = 0; n < NPARTS; ++n) gv[n] = gt[fl][n];
#pragma unroll
        for (int r = 0; r < 4; ++r) {
            const int tl = kh * 16 + q * 4 + r;
            const float v = red[kh][0][q * 4 + r][fl] + red[kh][1][q * 4 + r][fl]
                          + red[kh][2][q * 4 + r][fl] + red[kh][3][q * 4 + r][fl];
            const float av = v + cv;
            float* orow = out + (size_t)(tb * 64 + tl) * OUTF;
#pragma unroll
            for (int n = 0; n < NPARTS; ++n) {
                const int j = n * NSF + fg;
                if (j < OUTF) orow[j] = av + sxt[tl][n] * gv[n];
            }
        }
    }
}

extern "C" void kernel_launch(void* const* d_in, const int* in_sizes, int n_in,
                              void* d_out, int out_size, void* d_ws, size_t ws_size,
                              hipStream_t stream) {
    const float* x    = (const float*)d_in[0];
    const float* Wsel = (const float*)d_in[1];
    const float* bsel = (const float*)d_in[2];
    const float* Wexp = (const float*)d_in[3];
    const float* bexp = (const float*)d_in[4];
    const float* Wfc  = (const float*)d_in[5];
    const float* bfc  = (const float*)d_in[6];
    float* out = (float*)d_out;

    char* ws = (char*)d_ws;
    u16* xb    = (u16*)(ws + WS_XB);
    u16* bsw   = (u16*)(ws + WS_BSW);
    float* sxb = (float*)(ws + WS_SX);
    float* gcv = (float*)(ws + WS_GC);

    // launch 1: all preprocessing (sx | G/c | retile_x | retile_b)
    prep<<<dim3(128 + 14 + 8192 + 448), dim3(256), 0, stream>>>(
        x, Wsel, bsel, Wexp, bexp, Wfc, bfc, xb, bsw, sxb, gcv);
    // launch 2: main GEMM + fused epilogue
    main_kernel<<<dim3(13 * 64), dim3(256), 0, stream>>>(xb, bsw, sxb, gcv, out);
}

// Round 6
// 215.873 us; speedup vs baseline: 1.0545x; 1.0040x over previous
//
#include <hip/hip_runtime.h>
#include <hip/hip_bf16.h>
#include <stdint.h>

#define TKS    4096   // tokens = 2*2048
#define KD     4096   // in_features
#define NSF    410    // split_f
#define NPARTS 10
#define OUTF   4096

typedef unsigned short u16;
typedef __attribute__((ext_vector_type(8))) short bf16x8;
typedef __attribute__((ext_vector_type(4))) float f32x4;

// ---- workspace layout (sx/gc carved from unused bsw slabs 448..511) ----
#define WS_XB  0                                     // u16[4096*4096]  granule bf16 x (32-row tiles)
#define WS_BSW ((size_t)TKS * KD * 2)                // u16[512*4096]   granule bf16 Wfc (64-row tiles)
#define WS_SX  (WS_BSW + (size_t)448 * 512 * 8 * 2)  // f32[4096*10]    sx
#define WS_GC  (WS_SX + (size_t)TKS * NPARTS * 4)    // f32[448*12]     G (cols 0..9) + c (col 10)

__device__ inline u16 f2bf(float f) {
    union { __hip_bfloat16 b; u16 u; } cv;
    cv.b = __float2bfloat16(f);
    return cv.u;
}

// 64-row tile granule g in [0,512): slot=g>>6 = hi*4+ks*2+lo
// row = hi*32+lo*16+(g&15) ; col = ks*32+((g>>4)&3)*8   (conflict-free, proven)
__device__ inline int g_row(int g) { int s = g >> 6; return (s >> 2) * 32 + (s & 1) * 16 + (g & 15); }
__device__ inline int g_col(int g) { int s = g >> 6; return ((s >> 1) & 1) * 32 + ((g >> 4) & 3) * 8; }

// ============ prep: ALL preprocessing in ONE launch (unchanged from R5) ======
//   [0,128)          sx-f32   : sx = x*Wsel^T + bsel   (32 tok/blk)
//   [128,142)        G-f32    : G = Wfc*Wexp, c = Wfc*bexp + bfc (32 f/blk)
//   [142,8334)       retile_x : x (f32) -> xb (bf16 32-row granule tiles)
//   [8334,8782)      retile_b : Wfc (f32) -> bsw (bf16 64-row granule tiles)
__global__ __launch_bounds__(256) void prep(const float* __restrict__ x,
                                            const float* __restrict__ Wsel,
                                            const float* __restrict__ bsel,
                                            const float* __restrict__ Wexp,
                                            const float* __restrict__ bexp,
                                            const float* __restrict__ Wfc,
                                            const float* __restrict__ bfc,
                                            u16* __restrict__ xb,
                                            u16* __restrict__ bsw,
                                            float* __restrict__ sxb,
                                            float* __restrict__ gc) {
    const int bid = blockIdx.x;
    const int tid = threadIdx.x;

    if (bid < 128) {
        // -------- sx-f32: wave w owns 8 tokens, lanes split K 64-way --------
        const int b3 = bid;                         // 0..127
        const int w = tid >> 6, lane = tid & 63;
        const int t0 = b3 * 32 + w * 8;
        float acc[8][NPARTS];
#pragma unroll
        for (int t = 0; t < 8; ++t)
#pragma unroll
            for (int n = 0; n < NPARTS; ++n) acc[t][n] = 0.f;

        for (int k4 = 0; k4 < 16; ++k4) {           // k = k4*256 + lane*4
            const int k = k4 * 256 + lane * 4;
            float4 ws[NPARTS];
#pragma unroll
            for (int n = 0; n < NPARTS; ++n)
                ws[n] = *(const float4*)&Wsel[(size_t)n * KD + k];
#pragma unroll
            for (int t = 0; t < 8; ++t) {
                float4 xv = *(const float4*)&x[(size_t)(t0 + t) * KD + k];
#pragma unroll
                for (int n = 0; n < NPARTS; ++n)
                    acc[t][n] += xv.x * ws[n].x + xv.y * ws[n].y
                               + xv.z * ws[n].z + xv.w * ws[n].w;
            }
        }
        // butterfly reduce across 64 K-lanes
#pragma unroll
        for (int s = 1; s < 64; s <<= 1)
#pragma unroll
            for (int t = 0; t < 8; ++t)
#pragma unroll
                for (int n = 0; n < NPARTS; ++n)
                    acc[t][n] += __shfl_xor(acc[t][n], s);
        if (lane == 0) {
#pragma unroll
            for (int t = 0; t < 8; ++t)
#pragma unroll
                for (int n = 0; n < NPARTS; ++n)
                    sxb[(size_t)(t0 + t) * NPARTS + n] = acc[t][n] + bsel[n];
        }

    } else if (bid < 142) {
        // -------- G-f32: wave w owns 8 f-rows; col 10 = c (bexp dot) --------
        const int b4 = bid - 128;                   // 0..13
        const int w = tid >> 6, lane = tid & 63;
        const int f0 = b4 * 32 + w * 8;
        float acc[8][11];
#pragma unroll
        for (int t = 0; t < 8; ++t)
#pragma unroll
            for (int n = 0; n < 11; ++n) acc[t][n] = 0.f;

        for (int k4 = 0; k4 < 16; ++k4) {
            const int k = k4 * 256 + lane * 4;
            float we[4][11];
#pragma unroll
            for (int j = 0; j < 4; ++j) {
#pragma unroll
                for (int n = 0; n < NPARTS; ++n)
                    we[j][n] = Wexp[(size_t)(k + j) * NPARTS + n];
                we[j][10] = bexp[k + j];
            }
#pragma unroll
            for (int t = 0; t < 8; ++t) {
                const int f = f0 + t;
                float4 xv = (f < NSF) ? *(const float4*)&Wfc[(size_t)f * KD + k]
                                      : make_float4(0.f, 0.f, 0.f, 0.f);
#pragma unroll
                for (int n = 0; n < 11; ++n)
                    acc[t][n] += xv.x * we[0][n] + xv.y * we[1][n]
                               + xv.z * we[2][n] + xv.w * we[3][n];
            }
        }
#pragma unroll
        for (int s = 1; s < 64; s <<= 1)
#pragma unroll
            for (int t = 0; t < 8; ++t)
#pragma unroll
                for (int n = 0; n < 11; ++n)
                    acc[t][n] += __shfl_xor(acc[t][n], s);
        if (lane == 0) {
#pragma unroll
            for (int t = 0; t < 8; ++t) {
                const int f = f0 + t;
#pragma unroll
                for (int n = 0; n < NPARTS; ++n)
                    gc[(size_t)f * 12 + n] = (f < NSF) ? acc[t][n] : 0.f;
                gc[(size_t)f * 12 + 10] = (f < NSF) ? acc[t][10] + bfc[f] : 0.f;
            }
        }

    } else if (bid < 8334) {
        // -------- retile_x (unchanged logic) --------
        const int b1 = bid - 142;
        const int kt = b1 & 63, tb = b1 >> 6;       // tb 0..127
        const int g = tid;                          // granule 0..255
        const int slot = g >> 6;                    // ks*2+lo
        const int row = (slot & 1) * 16 + (g & 15);
        const int col = (slot >> 1) * 32 + ((g >> 4) & 3) * 8;
        const float* src = x + (size_t)(tb * 32 + row) * KD + kt * 64 + col;
        float4 v0 = *(const float4*)src;
        float4 v1 = *(const float4*)(src + 4);
        u16 h[8] = { f2bf(v0.x), f2bf(v0.y), f2bf(v0.z), f2bf(v0.w),
                     f2bf(v1.x), f2bf(v1.y), f2bf(v1.z), f2bf(v1.w) };
        *(uint4*)&xb[((size_t)(tb * 64 + kt) * 256 + g) * 8] = *(uint4*)h;

    } else {
        // -------- retile_b (unchanged logic) --------
        const int b2 = bid - 8334;
        const int kt = b2 & 63, rb = b2 >> 6;       // rb 0..6
        u16* tout = bsw + ((size_t)(rb * 64 + kt) * 512) * 8;
#pragma unroll
        for (int j = 0; j < 2; ++j) {
            const int g = j * 256 + tid;
            const int r = rb * 64 + g_row(g);
            uint4 pk = make_uint4(0u, 0u, 0u, 0u);
            if (r < NSF) {
                const float* src = Wfc + (size_t)r * KD + kt * 64 + g_col(g);
                float4 v0 = *(const float4*)src;
                float4 v1 = *(const float4*)(src + 4);
                u16 h[8] = { f2bf(v0.x), f2bf(v0.y), f2bf(v0.z), f2bf(v0.w),
                             f2bf(v1.x), f2bf(v1.y), f2bf(v1.z), f2bf(v1.w) };
                pk = *(uint4*)h;
            }
            *(uint4*)&tout[(size_t)g * 8] = pk;
        }
    }
}

// ============ main: zero-LDS K-loop, depth-4 pipeline PINNED via T19 =========
// R6 change: sched_group_barrier pins the unrolled program order the scheduler
// kept destroying (R3-R5 all emitted VGPR=52, ~6 loads in flight, 2 TB/s by
// Little's law). Ordered groups: [VMEM_READ x18 prologue], then per half-step
// [VMEM_READ x6][MFMA x8] -> 18-24 loads in flight per wave.
// Group accounting: 18 + 29*6 = 192 loads, 32*8 = 256 MFMAs (exact).
// grid 832 = 13 f2 x 64 tb (stride 64 % 8 == 0 keeps same-tb on one XCD).
#define A_IDX(kt, mi, ks) ((((size_t)(tb * 2 + ((mi) >> 1)) * 64 + (size_t)(kt)) * 256 \
                            + ((ks) * 2 + ((mi) & 1)) * 64 + lane) * 8)
#define B_IDX(kt, nj, ks) (((size_t)(fb * 64 + (kt)) * 512 \
                            + (wf * 4 + (ks) * 2 + (nj)) * 64 + lane) * 8)

__global__ __launch_bounds__(256, 2) void main_kernel(const u16* __restrict__ xb,
                                                      const u16* __restrict__ bsw,
                                                      const float* __restrict__ sxb,
                                                      const float* __restrict__ gc,
                                                      float* __restrict__ out) {
    // [mi][donor kh][row16][f pad 34]: stride 34 -> bank = (ml+8q)%32, 2-way = free
    __shared__ float red[4][4][16][34];   // 34.8 KB
    __shared__ float sxt[64][NPARTS];     // 2.5 KB
    __shared__ float gt[32][12];          // 1.5 KB

    const int tid = threadIdx.x;
    const int f2 = blockIdx.x >> 6;     // 0..12  (f2=13 would be all fg>=410)
    const int tb = blockIdx.x & 63;     // 0..63  (64-token tiles)
    const int lane = tid & 63;
    const int kh = tid >> 6;            // K-split wave id 0..3
    const int q = lane >> 4, ml = lane & 15;
    const int fb = f2 >> 1, wf = f2 & 1;

    f32x4 acc[4][2];
#pragma unroll
    for (int mi = 0; mi < 4; ++mi)
#pragma unroll
        for (int nj = 0; nj < 2; ++nj) acc[mi][nj] = (f32x4){0.f,0.f,0.f,0.f};

    bf16x8 fa[4][4], fbv[4][2];

#define LOADAB(p, kt, ks) do {                                            \
        _Pragma("unroll")                                                 \
        for (int mi = 0; mi < 4; ++mi)                                    \
            fa[p][mi] = *(const bf16x8*)&xb[A_IDX((kt), mi, (ks))];       \
        _Pragma("unroll")                                                 \
        for (int nj = 0; nj < 2; ++nj)                                    \
            fbv[p][nj] = *(const bf16x8*)&bsw[B_IDX((kt), nj, (ks))];     \
    } while (0)

#define MFMAS(p) do {                                                     \
        _Pragma("unroll")                                                 \
        for (int mi = 0; mi < 4; ++mi)                                    \
            _Pragma("unroll")                                             \
            for (int nj = 0; nj < 2; ++nj)                                \
                acc[mi][nj] = __builtin_amdgcn_mfma_f32_16x16x32_bf16(    \
                    fa[p][mi], fbv[p][nj], acc[mi][nj], 0, 0, 0);         \
    } while (0)

    // half-step s in [0,32): kt = kh*16 + (s>>1), ks = s&1
#define LD(p, s) LOADAB((p), kh * 16 + ((s) >> 1), (s) & 1)

    LD(0, 0); LD(1, 1); LD(2, 2);
    __builtin_amdgcn_sched_group_barrier(0x020, 18, 0);   // prologue: 18 VMEM_READ first
#pragma unroll
    for (int s = 0; s < 32; ++s) {
        if (s + 3 < 32) LD((s + 3) & 3, s + 3);
        MFMAS(s & 3);
        if (s + 3 < 32)
            __builtin_amdgcn_sched_group_barrier(0x020, 6, 0);  // this step's prefetch
        __builtin_amdgcn_sched_group_barrier(0x008, 8, 0);      // this step's MFMAs
    }
#undef LD
#undef LOADAB
#undef MFMAS

    // ---- K-reduce: wave kh publishes partials; owns row group kh after barrier
#pragma unroll
    for (int mi = 0; mi < 4; ++mi)
#pragma unroll
        for (int nj = 0; nj < 2; ++nj)
#pragma unroll
            for (int r = 0; r < 4; ++r)
                red[mi][kh][q * 4 + r][nj * 16 + ml] = acc[mi][nj][r];

    // stage sx / G tables (global -> LDS) while reduce data lands
    for (int i = tid; i < 64 * NPARTS; i += 256)
        sxt[i / NPARTS][i % NPARTS] = sxb[((size_t)tb * 64 + i / NPARTS) * NPARTS + i % NPARTS];
    for (int i = tid; i < 32 * 11; i += 256)
        gt[i / 11][i % 11] = gc[((size_t)f2 * 32 + i / 11) * 12 + i % 11];
    __syncthreads();

    // ---- epilogue: wave kh stores rows kh*16 .. kh*16+15 ----
#pragma unroll
    for (int nj = 0; nj < 2; ++nj) {
        const int fl = nj * 16 + ml;
        const int fg = f2 * 32 + fl;
        if (fg >= NSF) continue;
        const float cv = gt[fl][10];
        float gv[NPARTS];
#pragma unroll
        for (int n = 0; n < NPARTS; ++n) gv[n] = gt[fl][n];
#pragma unroll
        for (int r = 0; r < 4; ++r) {
            const int tl = kh * 16 + q * 4 + r;
            const float v = red[kh][0][q * 4 + r][fl] + red[kh][1][q * 4 + r][fl]
                          + red[kh][2][q * 4 + r][fl] + red[kh][3][q * 4 + r][fl];
            const float av = v + cv;
            float* orow = out + (size_t)(tb * 64 + tl) * OUTF;
#pragma unroll
            for (int n = 0; n < NPARTS; ++n) {
                const int j = n * NSF + fg;
                if (j < OUTF) orow[j] = av + sxt[tl][n] * gv[n];
            }
        }
    }
}

extern "C" void kernel_launch(void* const* d_in, const int* in_sizes, int n_in,
                              void* d_out, int out_size, void* d_ws, size_t ws_size,
                              hipStream_t stream) {
    const float* x    = (const float*)d_in[0];
    const float* Wsel = (const float*)d_in[1];
    const float* bsel = (const float*)d_in[2];
    const float* Wexp = (const float*)d_in[3];
    const float* bexp = (const float*)d_in[4];
    const float* Wfc  = (const float*)d_in[5];
    const float* bfc  = (const float*)d_in[6];
    float* out = (float*)d_out;

    char* ws = (char*)d_ws;
    u16* xb    = (u16*)(ws + WS_XB);
    u16* bsw   = (u16*)(ws + WS_BSW);
    float* sxb = (float*)(ws + WS_SX);
    float* gcv = (float*)(ws + WS_GC);

    // launch 1: all preprocessing (sx | G/c | retile_x | retile_b)
    prep<<<dim3(128 + 14 + 8192 + 448), dim3(256), 0, stream>>>(
        x, Wsel, bsel, Wexp, bexp, Wfc, bfc, xb, bsw, sxb, gcv);
    // launch 2: main GEMM + fused epilogue
    main_kernel<<<dim3(13 * 64), dim3(256), 0, stream>>>(xb, bsw, sxb, gcv, out);
}

// Round 7
// 206.503 us; speedup vs baseline: 1.1023x; 1.0454x over previous
//
#include <hip/hip_runtime.h>
#include <hip/hip_bf16.h>
#include <stdint.h>

#define TKS    4096   // tokens = 2*2048
#define KD     4096   // in_features
#define NSF    410    // split_f
#define NPARTS 10
#define OUTF   4096

typedef unsigned short u16;
typedef __attribute__((ext_vector_type(8))) short bf16x8;
typedef __attribute__((ext_vector_type(4))) float f32x4;

// ---- workspace layout (sx/gc carved from unused bsw slabs 448..511) ----
#define WS_XB  0                                     // u16[4096*4096]  granule bf16 x (32-row tiles)
#define WS_BSW ((size_t)TKS * KD * 2)                // u16[512*4096]   granule bf16 Wfc (64-row tiles)
#define WS_SX  (WS_BSW + (size_t)448 * 512 * 8 * 2)  // f32[4096*10]    sx
#define WS_GC  (WS_SX + (size_t)TKS * NPARTS * 4)    // f32[448*12]     G (cols 0..9) + c (col 10)

__device__ inline u16 f2bf(float f) {
    union { __hip_bfloat16 b; u16 u; } cv;
    cv.b = __float2bfloat16(f);
    return cv.u;
}

// 64-row tile granule g in [0,512): slot=g>>6 = hi*4+ks*2+lo
// row = hi*32+lo*16+(g&15) ; col = ks*32+((g>>4)&3)*8   (conflict-free, proven)
__device__ inline int g_row(int g) { int s = g >> 6; return (s >> 2) * 32 + (s & 1) * 16 + (g & 15); }
__device__ inline int g_col(int g) { int s = g >> 6; return ((s >> 1) & 1) * 32 + ((g >> 4) & 3) * 8; }

// ============ prep: ALL preprocessing in ONE launch (unchanged from R5) ======
//   [0,128)          sx-f32   : sx = x*Wsel^T + bsel   (32 tok/blk)
//   [128,142)        G-f32    : G = Wfc*Wexp, c = Wfc*bexp + bfc (32 f/blk)
//   [142,8334)       retile_x : x (f32) -> xb (bf16 32-row granule tiles)
//   [8334,8782)      retile_b : Wfc (f32) -> bsw (bf16 64-row granule tiles)
__global__ __launch_bounds__(256) void prep(const float* __restrict__ x,
                                            const float* __restrict__ Wsel,
                                            const float* __restrict__ bsel,
                                            const float* __restrict__ Wexp,
                                            const float* __restrict__ bexp,
                                            const float* __restrict__ Wfc,
                                            const float* __restrict__ bfc,
                                            u16* __restrict__ xb,
                                            u16* __restrict__ bsw,
                                            float* __restrict__ sxb,
                                            float* __restrict__ gc) {
    const int bid = blockIdx.x;
    const int tid = threadIdx.x;

    if (bid < 128) {
        // -------- sx-f32: wave w owns 8 tokens, lanes split K 64-way --------
        const int b3 = bid;                         // 0..127
        const int w = tid >> 6, lane = tid & 63;
        const int t0 = b3 * 32 + w * 8;
        float acc[8][NPARTS];
#pragma unroll
        for (int t = 0; t < 8; ++t)
#pragma unroll
            for (int n = 0; n < NPARTS; ++n) acc[t][n] = 0.f;

        for (int k4 = 0; k4 < 16; ++k4) {           // k = k4*256 + lane*4
            const int k = k4 * 256 + lane * 4;
            float4 ws[NPARTS];
#pragma unroll
            for (int n = 0; n < NPARTS; ++n)
                ws[n] = *(const float4*)&Wsel[(size_t)n * KD + k];
#pragma unroll
            for (int t = 0; t < 8; ++t) {
                float4 xv = *(const float4*)&x[(size_t)(t0 + t) * KD + k];
#pragma unroll
                for (int n = 0; n < NPARTS; ++n)
                    acc[t][n] += xv.x * ws[n].x + xv.y * ws[n].y
                               + xv.z * ws[n].z + xv.w * ws[n].w;
            }
        }
        // butterfly reduce across 64 K-lanes
#pragma unroll
        for (int s = 1; s < 64; s <<= 1)
#pragma unroll
            for (int t = 0; t < 8; ++t)
#pragma unroll
                for (int n = 0; n < NPARTS; ++n)
                    acc[t][n] += __shfl_xor(acc[t][n], s);
        if (lane == 0) {
#pragma unroll
            for (int t = 0; t < 8; ++t)
#pragma unroll
                for (int n = 0; n < NPARTS; ++n)
                    sxb[(size_t)(t0 + t) * NPARTS + n] = acc[t][n] + bsel[n];
        }

    } else if (bid < 142) {
        // -------- G-f32: wave w owns 8 f-rows; col 10 = c (bexp dot) --------
        const int b4 = bid - 128;                   // 0..13
        const int w = tid >> 6, lane = tid & 63;
        const int f0 = b4 * 32 + w * 8;
        float acc[8][11];
#pragma unroll
        for (int t = 0; t < 8; ++t)
#pragma unroll
            for (int n = 0; n < 11; ++n) acc[t][n] = 0.f;

        for (int k4 = 0; k4 < 16; ++k4) {
            const int k = k4 * 256 + lane * 4;
            float we[4][11];
#pragma unroll
            for (int j = 0; j < 4; ++j) {
#pragma unroll
                for (int n = 0; n < NPARTS; ++n)
                    we[j][n] = Wexp[(size_t)(k + j) * NPARTS + n];
                we[j][10] = bexp[k + j];
            }
#pragma unroll
            for (int t = 0; t < 8; ++t) {
                const int f = f0 + t;
                float4 xv = (f < NSF) ? *(const float4*)&Wfc[(size_t)f * KD + k]
                                      : make_float4(0.f, 0.f, 0.f, 0.f);
#pragma unroll
                for (int n = 0; n < 11; ++n)
                    acc[t][n] += xv.x * we[0][n] + xv.y * we[1][n]
                               + xv.z * we[2][n] + xv.w * we[3][n];
            }
        }
#pragma unroll
        for (int s = 1; s < 64; s <<= 1)
#pragma unroll
            for (int t = 0; t < 8; ++t)
#pragma unroll
                for (int n = 0; n < 11; ++n)
                    acc[t][n] += __shfl_xor(acc[t][n], s);
        if (lane == 0) {
#pragma unroll
            for (int t = 0; t < 8; ++t) {
                const int f = f0 + t;
#pragma unroll
                for (int n = 0; n < NPARTS; ++n)
                    gc[(size_t)f * 12 + n] = (f < NSF) ? acc[t][n] : 0.f;
                gc[(size_t)f * 12 + 10] = (f < NSF) ? acc[t][10] + bfc[f] : 0.f;
            }
        }

    } else if (bid < 8334) {
        // -------- retile_x (unchanged logic) --------
        const int b1 = bid - 142;
        const int kt = b1 & 63, tb = b1 >> 6;       // tb 0..127
        const int g = tid;                          // granule 0..255
        const int slot = g >> 6;                    // ks*2+lo
        const int row = (slot & 1) * 16 + (g & 15);
        const int col = (slot >> 1) * 32 + ((g >> 4) & 3) * 8;
        const float* src = x + (size_t)(tb * 32 + row) * KD + kt * 64 + col;
        float4 v0 = *(const float4*)src;
        float4 v1 = *(const float4*)(src + 4);
        u16 h[8] = { f2bf(v0.x), f2bf(v0.y), f2bf(v0.z), f2bf(v0.w),
                     f2bf(v1.x), f2bf(v1.y), f2bf(v1.z), f2bf(v1.w) };
        *(uint4*)&xb[((size_t)(tb * 64 + kt) * 256 + g) * 8] = *(uint4*)h;

    } else {
        // -------- retile_b (unchanged logic) --------
        const int b2 = bid - 8334;
        const int kt = b2 & 63, rb = b2 >> 6;       // rb 0..6
        u16* tout = bsw + ((size_t)(rb * 64 + kt) * 512) * 8;
#pragma unroll
        for (int j = 0; j < 2; ++j) {
            const int g = j * 256 + tid;
            const int r = rb * 64 + g_row(g);
            uint4 pk = make_uint4(0u, 0u, 0u, 0u);
            if (r < NSF) {
                const float* src = Wfc + (size_t)r * KD + kt * 64 + g_col(g);
                float4 v0 = *(const float4*)src;
                float4 v1 = *(const float4*)(src + 4);
                u16 h[8] = { f2bf(v0.x), f2bf(v0.y), f2bf(v0.z), f2bf(v0.w),
                             f2bf(v1.x), f2bf(v1.y), f2bf(v1.z), f2bf(v1.w) };
                pk = *(uint4*)h;
            }
            *(uint4*)&tout[(size_t)g * 8] = pk;
        }
    }
}

// ============ main: zero-LDS K-loop (T19-pinned), C-only epilogue ============
// R7 change: every round R0-R6 hit a ~68 us floor = WRITE_SIZE ~98 MB at
// 1.42 TB/s (10-way 128B scatter per token-row -> 1.53x partial-sector RMW).
// Now the epilogue stores ONLY the dense 6.7 MB GEMM result C[t][fg] into the
// first 410 columns of each out row; the expand kernel does sx*G + c and the
// dense 64 MB write. K-loop unchanged from R6.
#define A_IDX(kt, mi, ks) ((((size_t)(tb * 2 + ((mi) >> 1)) * 64 + (size_t)(kt)) * 256 \
                            + ((ks) * 2 + ((mi) & 1)) * 64 + lane) * 8)
#define B_IDX(kt, nj, ks) (((size_t)(fb * 64 + (kt)) * 512 \
                            + (wf * 4 + (ks) * 2 + (nj)) * 64 + lane) * 8)

__global__ __launch_bounds__(256, 2) void main_kernel(const u16* __restrict__ xb,
                                                      const u16* __restrict__ bsw,
                                                      float* __restrict__ out) {
    // [mi][donor kh][row16][f pad 34]: stride 34 -> bank = (ml+8q)%32, 2-way = free
    __shared__ float red[4][4][16][34];   // 34.8 KB

    const int tid = threadIdx.x;
    const int f2 = blockIdx.x >> 6;     // 0..12  (f2=13 would be all fg>=410)
    const int tb = blockIdx.x & 63;     // 0..63  (64-token tiles)
    const int lane = tid & 63;
    const int kh = tid >> 6;            // K-split wave id 0..3
    const int q = lane >> 4, ml = lane & 15;
    const int fb = f2 >> 1, wf = f2 & 1;

    f32x4 acc[4][2];
#pragma unroll
    for (int mi = 0; mi < 4; ++mi)
#pragma unroll
        for (int nj = 0; nj < 2; ++nj) acc[mi][nj] = (f32x4){0.f,0.f,0.f,0.f};

    bf16x8 fa[4][4], fbv[4][2];

#define LOADAB(p, kt, ks) do {                                            \
        _Pragma("unroll")                                                 \
        for (int mi = 0; mi < 4; ++mi)                                    \
            fa[p][mi] = *(const bf16x8*)&xb[A_IDX((kt), mi, (ks))];       \
        _Pragma("unroll")                                                 \
        for (int nj = 0; nj < 2; ++nj)                                    \
            fbv[p][nj] = *(const bf16x8*)&bsw[B_IDX((kt), nj, (ks))];     \
    } while (0)

#define MFMAS(p) do {                                                     \
        _Pragma("unroll")                                                 \
        for (int mi = 0; mi < 4; ++mi)                                    \
            _Pragma("unroll")                                             \
            for (int nj = 0; nj < 2; ++nj)                                \
                acc[mi][nj] = __builtin_amdgcn_mfma_f32_16x16x32_bf16(    \
                    fa[p][mi], fbv[p][nj], acc[mi][nj], 0, 0, 0);         \
    } while (0)

    // half-step s in [0,32): kt = kh*16 + (s>>1), ks = s&1
#define LD(p, s) LOADAB((p), kh * 16 + ((s) >> 1), (s) & 1)

    LD(0, 0); LD(1, 1); LD(2, 2);
    __builtin_amdgcn_sched_group_barrier(0x020, 18, 0);   // prologue: 18 VMEM_READ first
#pragma unroll
    for (int s = 0; s < 32; ++s) {
        if (s + 3 < 32) LD((s + 3) & 3, s + 3);
        MFMAS(s & 3);
        if (s + 3 < 32)
            __builtin_amdgcn_sched_group_barrier(0x020, 6, 0);  // this step's prefetch
        __builtin_amdgcn_sched_group_barrier(0x008, 8, 0);      // this step's MFMAs
    }
#undef LD
#undef LOADAB
#undef MFMAS

    // ---- K-reduce: wave kh publishes partials; owns row group kh after barrier
#pragma unroll
    for (int mi = 0; mi < 4; ++mi)
#pragma unroll
        for (int nj = 0; nj < 2; ++nj)
#pragma unroll
            for (int r = 0; r < 4; ++r)
                red[mi][kh][q * 4 + r][nj * 16 + ml] = acc[mi][nj][r];
    __syncthreads();

    // ---- epilogue: store dense C rows (f32) into out[t][0..409] ----
#pragma unroll
    for (int nj = 0; nj < 2; ++nj) {
        const int fl = nj * 16 + ml;
        const int fg = f2 * 32 + fl;
        if (fg >= NSF) continue;
#pragma unroll
        for (int r = 0; r < 4; ++r) {
            const int tl = kh * 16 + q * 4 + r;
            const float v = red[kh][0][q * 4 + r][fl] + red[kh][1][q * 4 + r][fl]
                          + red[kh][2][q * 4 + r][fl] + red[kh][3][q * 4 + r][fl];
            out[(size_t)(tb * 64 + tl) * OUTF + fg] = v;
        }
    }
}

// ============ expand: out[t][j] = C[t][fg] + sx[t][n]*G[fg][n] + c[fg] =======
// 1024 blocks x 4 tokens. C lives in out[t][0..409]; staged to LDS before the
// dense overwrite (same block owns its rows exclusively -> no hazard).
// Store pattern: thread writes float4 at j = g*1024 + tid*4 -> each store
// instruction covers 1 KB contiguous per wave (full 64B sectors, no RMW).
__global__ __launch_bounds__(256) void expand(const float* __restrict__ sxb,
                                              const float* __restrict__ gc,
                                              float* out) {
    __shared__ float Ct[4][412];
    __shared__ float sxl[4][NPARTS];
    const int tid = threadIdx.x;
    const int t0 = blockIdx.x * 4;

    // per-thread column constants: j = g*1024 + tid*4 + e  (fully unrolled ->
    // static indexing, no scratch)
    int   ns[4][4], fgs[4][4];
    float gv[4][4], cv[4][4];
#pragma unroll
    for (int g = 0; g < 4; ++g)
#pragma unroll
        for (int e = 0; e < 4; ++e) {
            const int j = g * 1024 + tid * 4 + e;
            const int n = j / NSF;                 // 0..9
            const int fg = j - n * NSF;
            ns[g][e] = n; fgs[g][e] = fg;
            gv[g][e] = gc[(size_t)fg * 12 + n];
            cv[g][e] = gc[(size_t)fg * 12 + 10];
        }

    // stage C tile + sx
    for (int i = tid; i < 4 * NSF; i += 256)
        Ct[i / NSF][i % NSF] = out[(size_t)(t0 + i / NSF) * OUTF + (i % NSF)];
    if (tid < 4 * NPARTS)
        sxl[tid / NPARTS][tid % NPARTS] =
            sxb[(size_t)(t0 + tid / NPARTS) * NPARTS + tid % NPARTS];
    __syncthreads();

#pragma unroll
    for (int r = 0; r < 4; ++r) {
        float* orow = out + (size_t)(t0 + r) * OUTF;
#pragma unroll
        for (int g = 0; g < 4; ++g) {
            float4 v;
            v.x = Ct[r][fgs[g][0]] + sxl[r][ns[g][0]] * gv[g][0] + cv[g][0];
            v.y = Ct[r][fgs[g][1]] + sxl[r][ns[g][1]] * gv[g][1] + cv[g][1];
            v.z = Ct[r][fgs[g][2]] + sxl[r][ns[g][2]] * gv[g][2] + cv[g][2];
            v.w = Ct[r][fgs[g][3]] + sxl[r][ns[g][3]] * gv[g][3] + cv[g][3];
            *(float4*)&orow[g * 1024 + tid * 4] = v;
        }
    }
}

extern "C" void kernel_launch(void* const* d_in, const int* in_sizes, int n_in,
                              void* d_out, int out_size, void* d_ws, size_t ws_size,
                              hipStream_t stream) {
    const float* x    = (const float*)d_in[0];
    const float* Wsel = (const float*)d_in[1];
    const float* bsel = (const float*)d_in[2];
    const float* Wexp = (const float*)d_in[3];
    const float* bexp = (const float*)d_in[4];
    const float* Wfc  = (const float*)d_in[5];
    const float* bfc  = (const float*)d_in[6];
    float* out = (float*)d_out;

    char* ws = (char*)d_ws;
    u16* xb    = (u16*)(ws + WS_XB);
    u16* bsw   = (u16*)(ws + WS_BSW);
    float* sxb = (float*)(ws + WS_SX);
    float* gcv = (float*)(ws + WS_GC);

    // launch 1: all preprocessing (sx | G/c | retile_x | retile_b)
    prep<<<dim3(128 + 14 + 8192 + 448), dim3(256), 0, stream>>>(
        x, Wsel, bsel, Wexp, bexp, Wfc, bfc, xb, bsw, sxb, gcv);
    // launch 2: GEMM -> dense C (first 410 cols of each out row)
    main_kernel<<<dim3(13 * 64), dim3(256), 0, stream>>>(xb, bsw, out);
    // launch 3: dense expansion out = C + sx*G + c
    expand<<<dim3(1024), dim3(256), 0, stream>>>(sxb, gcv, out);
}